// Round 15
// baseline (60.989 us; speedup 1.0000x reference)
//
#include <hip/hip_runtime.h>

// Problem shapes (fixed by setup_inputs)
#define B_  16
#define TE_ 256
#define TD_ 128
#define H_  512

#define C_TANH 2.88539008177792681472f  // 2*log2(e):  tanh(x) = 1 - 2/(exp2(C*x)+1)
#define LOG2E  1.44269504088896340736f

typedef __attribute__((ext_vector_type(8))) short short8v;   // 8 x bf16 (4 VGPR)
typedef __attribute__((ext_vector_type(4))) float floatx4;   // MFMA acc

__device__ __forceinline__ float wave_sum(float v) {
#pragma unroll
  for (int m = 32; m; m >>= 1) v += __shfl_xor(v, m, 64);
  return v;
}
__device__ __forceinline__ float wave_max(float v) {
#pragma unroll
  for (int m = 32; m; m >>= 1) v = fmaxf(v, __shfl_xor(v, m, 64));
  return v;
}
__device__ __forceinline__ ushort f2bf(float f) {  // RNE fp32->bf16
  unsigned u = __builtin_bit_cast(unsigned, f);
  u += 0x7fffu + ((u >> 16) & 1u);
  return (ushort)(u >> 16);
}
__device__ __forceinline__ float bf2f(ushort u) {
  return __builtin_bit_cast(float, (unsigned)u << 16);
}
__device__ __forceinline__ unsigned pk2(float a, float b) {
  return (unsigned)f2bf(a) | ((unsigned)f2bf(b) << 16);
}

// ---------------------------------------------------------------------------
// GEMM core: BM=64 BN=128 BK=64, 4 waves (256 thr), 2-phase reg pipeline.
// 16 MFMAs per wave between each barrier pair (2 k-slices x 8 n-tiles).
// LDS: A [2][64][40] ushort (10 KB), B [2][128][40] ushort (20 KB).
// Operand modes:
//   MA: 0 = bf16 [m][k] direct; 1 = f32 [m][k] cvt; 2 = f32 [k][64-col] transp
//   MB: 1 = f32 [n][k] cvt;     2 = f32 [k][128-col] transposed staging
// arow0/bcol0: tile base in the non-k dim of that operand.
// ---------------------------------------------------------------------------
template <int MA, int MB>
__device__ __forceinline__ void gemm_core128(
    const void* Asrc, const void* Bsrc, long lda, long ldb, int K,
    int arow0, int bcol0, ushort* As, ushort* Bs, floatx4* acc)
{
  constexpr int ASL = 2560;   // ushorts per A k-slice (64*40)
  constexpr int BSL = 5120;   // ushorts per B k-slice (128*40)
  const int tid = threadIdx.x;
  const int l = tid & 63, w = tid >> 6;
  const int l15 = l & 15, l4 = l >> 4;

  // row-chunk staging map (modes 0/1): row = q*32 + (tid>>3), kg = tid&7
  const int sr = tid >> 3, kg = tid & 7;
  const int dsRC = (kg >> 2) * 0 + 0;  // placeholder (per-operand below)
  const int kcA = ((kg & 3) << 3);
  const int ksA = (kg >> 2);
  // transpose staging map (mode 2): kp = k-pair, hg = 8-col group
  const int kpA = tid >> 3, hgA = tid & 7;                 // A: 64 cols
  const int dsTA = (kpA >> 4) * ASL + ((kpA << 1) & 31);
  const int hgB = tid & 15;                                // B: 128 cols
  // B mode2: unit q handles k-slice q: kp_q = q*16 + (tid>>4)

  const float*  Af = (const float*)Asrc;
  const ushort* Ab = (const ushort*)Asrc;
  const float*  Bf = (const float*)Bsrc;

  short8v a0r[2];
  float4 fa[4];
  float4 fb[8];

  auto LD = [&](int kt) {
    if constexpr (MA == 0) {
#pragma unroll
      for (int q = 0; q < 2; ++q)
        a0r[q] = *(const short8v*)(Ab + (long)(arow0 + q * 32 + sr) * lda + kt + kg * 8);
    } else if constexpr (MA == 1) {
#pragma unroll
      for (int q = 0; q < 2; ++q) {
        const long o = (long)(arow0 + q * 32 + sr) * lda + kt + kg * 8;
        fa[2 * q]     = *(const float4*)(Af + o);
        fa[2 * q + 1] = *(const float4*)(Af + o + 4);
      }
    } else {  // MA == 2
      const long base = (long)(kt + 2 * kpA) * lda + arow0 + hgA * 8;
      fa[0] = *(const float4*)(Af + base);
      fa[1] = *(const float4*)(Af + base + 4);
      fa[2] = *(const float4*)(Af + base + lda);
      fa[3] = *(const float4*)(Af + base + lda + 4);
    }
    if constexpr (MB == 1) {
#pragma unroll
      for (int q = 0; q < 4; ++q) {
        const long o = (long)(bcol0 + q * 32 + sr) * ldb + kt + kg * 8;
        fb[2 * q]     = *(const float4*)(Bf + o);
        fb[2 * q + 1] = *(const float4*)(Bf + o + 4);
      }
    } else {  // MB == 2
#pragma unroll
      for (int q = 0; q < 2; ++q) {
        const int kpq = q * 16 + (tid >> 4);
        const long base = (long)(kt + 2 * kpq) * ldb + bcol0 + hgB * 8;
        fb[4 * q + 0] = *(const float4*)(Bf + base);
        fb[4 * q + 1] = *(const float4*)(Bf + base + 4);
        fb[4 * q + 2] = *(const float4*)(Bf + base + ldb);
        fb[4 * q + 3] = *(const float4*)(Bf + base + ldb + 4);
      }
    }
  };
  auto ST = [&]() {
    if constexpr (MA == 0) {
#pragma unroll
      for (int q = 0; q < 2; ++q)
        *(short8v*)&As[ksA * ASL + (q * 32 + sr) * 40 + kcA] = a0r[q];
    } else if constexpr (MA == 1) {
#pragma unroll
      for (int q = 0; q < 2; ++q) {
        uint4 p = {pk2(fa[2 * q].x, fa[2 * q].y), pk2(fa[2 * q].z, fa[2 * q].w),
                   pk2(fa[2 * q + 1].x, fa[2 * q + 1].y),
                   pk2(fa[2 * q + 1].z, fa[2 * q + 1].w)};
        *(uint4*)&As[ksA * ASL + (q * 32 + sr) * 40 + kcA] = p;
      }
    } else {  // MA == 2
      const int h0 = hgA * 8;
      *(unsigned*)&As[dsTA + (h0 + 0) * 40] = pk2(fa[0].x, fa[2].x);
      *(unsigned*)&As[dsTA + (h0 + 1) * 40] = pk2(fa[0].y, fa[2].y);
      *(unsigned*)&As[dsTA + (h0 + 2) * 40] = pk2(fa[0].z, fa[2].z);
      *(unsigned*)&As[dsTA + (h0 + 3) * 40] = pk2(fa[0].w, fa[2].w);
      *(unsigned*)&As[dsTA + (h0 + 4) * 40] = pk2(fa[1].x, fa[3].x);
      *(unsigned*)&As[dsTA + (h0 + 5) * 40] = pk2(fa[1].y, fa[3].y);
      *(unsigned*)&As[dsTA + (h0 + 6) * 40] = pk2(fa[1].z, fa[3].z);
      *(unsigned*)&As[dsTA + (h0 + 7) * 40] = pk2(fa[1].w, fa[3].w);
    }
    if constexpr (MB == 1) {
#pragma unroll
      for (int q = 0; q < 4; ++q) {
        uint4 p = {pk2(fb[2 * q].x, fb[2 * q].y), pk2(fb[2 * q].z, fb[2 * q].w),
                   pk2(fb[2 * q + 1].x, fb[2 * q + 1].y),
                   pk2(fb[2 * q + 1].z, fb[2 * q + 1].w)};
        *(uint4*)&Bs[ksA * BSL + (q * 32 + sr) * 40 + kcA] = p;
      }
    } else {  // MB == 2
#pragma unroll
      for (int q = 0; q < 2; ++q) {
        const int kpq = q * 16 + (tid >> 4);
        const int dsTB = q * BSL + ((kpq << 1) & 31);
        const int h0 = hgB * 8;
        *(unsigned*)&Bs[dsTB + (h0 + 0) * 40] = pk2(fb[4 * q + 0].x, fb[4 * q + 2].x);
        *(unsigned*)&Bs[dsTB + (h0 + 1) * 40] = pk2(fb[4 * q + 0].y, fb[4 * q + 2].y);
        *(unsigned*)&Bs[dsTB + (h0 + 2) * 40] = pk2(fb[4 * q + 0].z, fb[4 * q + 2].z);
        *(unsigned*)&Bs[dsTB + (h0 + 3) * 40] = pk2(fb[4 * q + 0].w, fb[4 * q + 2].w);
        *(unsigned*)&Bs[dsTB + (h0 + 4) * 40] = pk2(fb[4 * q + 1].x, fb[4 * q + 3].x);
        *(unsigned*)&Bs[dsTB + (h0 + 5) * 40] = pk2(fb[4 * q + 1].y, fb[4 * q + 3].y);
        *(unsigned*)&Bs[dsTB + (h0 + 6) * 40] = pk2(fb[4 * q + 1].z, fb[4 * q + 3].z);
        *(unsigned*)&Bs[dsTB + (h0 + 7) * 40] = pk2(fb[4 * q + 1].w, fb[4 * q + 3].w);
      }
    }
  };

  LD(0);
  for (int kt = 0; kt < K; kt += 64) {
    if (kt) __syncthreads();
    ST();
    __syncthreads();
    if (kt + 64 < K) LD(kt + 64);   // flies under the MFMAs
#pragma unroll
    for (int kk = 0; kk < 2; ++kk) {
      short8v av = *(short8v*)&As[kk * ASL + (w * 16 + l15) * 40 + l4 * 8];
#pragma unroll
      for (int nt = 0; nt < 8; ++nt) {
        short8v bv = *(short8v*)&Bs[kk * BSL + (nt * 16 + l15) * 40 + l4 * 8];
        acc[nt] = __builtin_amdgcn_mfma_f32_16x16x32_bf16(av, bv, acc[nt], 0, 0, 0);
      }
    }
  }
}

// ---------------------------------------------------------------------------
// Fused phase-A, 384 blocks, XCD-aligned with energies consumer (id&7 = XCD
// -> b in {2x,2x+1}). Wa/Ua staged transposed on the fly.
//  ids [0,256):  A1-flipped: E_T[b][h][t] = bf16(exp2(C*(Wa^T . enc)))
//                A = Wa f32 [k][h64] mode2; B = enc f32 [m][k] mode1 (BN=128)
//  ids [256,384): A2: eU[m][h] = exp2(C*(dec . Ua)) f32 row-major
//                A = dec f32 [m][k] mode1; B = Ua f32 [k][h128] mode2
// ---------------------------------------------------------------------------
__global__ __launch_bounds__(256) void gemm_phaseA(
    const float* __restrict__ enc, const float* __restrict__ Wa,
    ushort* __restrict__ E_T,
    const float* __restrict__ dec, const float* __restrict__ Ua,
    float* __restrict__ eU)
{
  __shared__ __attribute__((aligned(16))) ushort As[5120];
  __shared__ __attribute__((aligned(16))) ushort Bs[10240];

  const int tid = threadIdx.x;
  const int l = tid & 63, w = tid >> 6;
  const int l15 = l & 15, l4 = l >> 4;
  const int id = blockIdx.x;

  floatx4 acc[8] = {};

  if (id < 256) {
    const int x = id & 7, k = id >> 3;     // k 0..31
    const int bm = k >> 2;                 // h-tile 0..7 (64-wide)
    const int bn = x * 4 + (k & 3);        // m-tile 0..31 (128-wide), b = bn>>1
    gemm_core128<2, 1>(Wa, enc, H_, H_, H_, bm * 64, bn * 128, As, Bs, acc);
    const int bb = bn >> 1, t0 = (bn & 1) * 128;
    const int hb = bm * 64 + w * 16 + (l4 << 2);
#pragma unroll
    for (int nt = 0; nt < 8; ++nt) {
      const int t = t0 + nt * 16 + l15;
#pragma unroll
      for (int r = 0; r < 4; ++r)
        E_T[((size_t)bb * H_ + hb + r) * TE_ + t] =
            f2bf(__builtin_amdgcn_exp2f(C_TANH * acc[nt][r]));
    }
  } else {
    const int i2 = id - 256;
    const int x = i2 & 7, k = i2 >> 3;     // k 0..15
    const int bm = x * 4 + (k & 3);        // m-tile 0..31 (64-wide), b = bm>>1
    const int bn = k >> 2;                 // h-tile 0..3 (128-wide)
    gemm_core128<1, 2>(dec, Ua, H_, H_, H_, bm * 64, bn * 128, As, Bs, acc);
    const int growb = bm * 64 + w * 16 + (l4 << 2);
#pragma unroll
    for (int nt = 0; nt < 8; ++nt) {
      const int gcol = bn * 128 + nt * 16 + l15;
#pragma unroll
      for (int r = 0; r < 4; ++r)
        eU[(size_t)(growb + r) * H_ + gcol] =
            __builtin_amdgcn_exp2f(C_TANH * acc[nt][r]);
    }
  }
}

// ---------------------------------------------------------------------------
// Phase-C GEMM: c[b] = eB[b] @ enc[b], enc staged transposed (mode 2).
// BN=128: grid (4, 2, 16) = 128 blocks. K = TE = 256.
// ---------------------------------------------------------------------------
__global__ __launch_bounds__(256) void gemm_ctx(
    const ushort* __restrict__ eB, const float* __restrict__ enc,
    float* __restrict__ C)
{
  __shared__ __attribute__((aligned(16))) ushort As[5120];
  __shared__ __attribute__((aligned(16))) ushort Bs[10240];

  const int tid = threadIdx.x;
  const int l = tid & 63, w = tid >> 6;
  const int l15 = l & 15, l4 = l >> 4;
  const long z = blockIdx.z;
  const int bm = blockIdx.y, bn = blockIdx.x;

  floatx4 acc[8] = {};
  gemm_core128<0, 2>(eB + z * TD_ * TE_, enc + z * (long)TE_ * H_,
                     TE_, H_, TE_, bm * 64, bn * 128, As, Bs, acc);

  const int growb = bm * 64 + w * 16 + (l4 << 2);
#pragma unroll
  for (int nt = 0; nt < 8; ++nt) {
    const int gcol = bn * 128 + nt * 16 + l15;
#pragma unroll
    for (int r = 0; r < 4; ++r)
      C[(z * TD_ + growb + r) * (long)H_ + gcol] = acc[nt][r];
  }
}

// ---------------------------------------------------------------------------
// Energies + softmax (round-13 verbatim): 4-way h-merged reciprocal.
//   Sum_{i=0..3} V_i/d_i = [(V0 d1 + V1 d0)q + (V2 d3 + V3 d2)p] / (p q),
//   d_i = 1 + E_i U_i. l = -2p (softmax shift-invariant).
// 1024 blocks (XCD x -> b in {2x,2x+1}), 8 waves; block = (b, 2 d rows);
// wave w owns h in [64w,64w+64) for both d rows; lane owns t-quad.
// ---------------------------------------------------------------------------
__global__ __launch_bounds__(512) void energies_softmax(
    const ushort* __restrict__ E_T, const float* __restrict__ eU,
    const float* __restrict__ Va, float* __restrict__ e_out,
    ushort* __restrict__ eB)
{
  __shared__ float part[2][8][TE_];

  const int tid  = threadIdx.x;
  const int lane = tid & 63;
  const int wv   = __builtin_amdgcn_readfirstlane(tid >> 6);  // h-eighth
  const int id   = blockIdx.x;            // 0..1023
  const int xcd  = id & 7, j = id >> 3;   // XCD x -> b in {2x, 2x+1}
  const int b    = (xcd << 1) | (j >> 6);
  const int d0   = (j & 63) << 1;

  const float* u0 = eU + (size_t)(b * TD_ + d0 + 0) * H_ + wv * 64;
  const float* u1 = eU + (size_t)(b * TD_ + d0 + 1) * H_ + wv * 64;
  const float* vp = Va + wv * 64;
  const ushort* ep = E_T + ((size_t)(b * H_) + wv * 64) * TE_ + (lane << 2);

  float p0[4] = {}, p1[4] = {};

#pragma unroll 2
  for (int hq = 0; hq < 16; ++hq) {
    const float4 vq  = *(const float4*)(vp + hq * 4);
    const float4 uq0 = *(const float4*)(u0 + hq * 4);
    const float4 uq1 = *(const float4*)(u1 + hq * 4);
    const ushort4 w0 = *(const ushort4*)(ep + (size_t)(hq * 4 + 0) * TE_);
    const ushort4 w1 = *(const ushort4*)(ep + (size_t)(hq * 4 + 1) * TE_);
    const ushort4 w2 = *(const ushort4*)(ep + (size_t)(hq * 4 + 2) * TE_);
    const ushort4 w3 = *(const ushort4*)(ep + (size_t)(hq * 4 + 3) * TE_);
    const float eh0[4] = {bf2f(w0.x), bf2f(w0.y), bf2f(w0.z), bf2f(w0.w)};
    const float eh1[4] = {bf2f(w1.x), bf2f(w1.y), bf2f(w1.z), bf2f(w1.w)};
    const float eh2[4] = {bf2f(w2.x), bf2f(w2.y), bf2f(w2.z), bf2f(w2.w)};
    const float eh3[4] = {bf2f(w3.x), bf2f(w3.y), bf2f(w3.z), bf2f(w3.w)};
#pragma unroll
    for (int t = 0; t < 4; ++t) {
      {  // d-row 0
        float d1 = fmaf(eh0[t], uq0.x, 1.f);
        float d2 = fmaf(eh1[t], uq0.y, 1.f);
        float d3 = fmaf(eh2[t], uq0.z, 1.f);
        float d4 = fmaf(eh3[t], uq0.w, 1.f);
        float p = d1 * d2, q = d3 * d4;
        float n12 = fmaf(vq.y, d1, vq.x * d2);
        float n34 = fmaf(vq.w, d3, vq.z * d4);
        float N = fmaf(n34, p, n12 * q);
        float r = __builtin_amdgcn_rcpf(p * q);
        p0[t] = fmaf(N, r, p0[t]);
      }
      {  // d-row 1
        float d1 = fmaf(eh0[t], uq1.x, 1.f);
        float d2 = fmaf(eh1[t], uq1.y, 1.f);
        float d3 = fmaf(eh2[t], uq1.z, 1.f);
        float d4 = fmaf(eh3[t], uq1.w, 1.f);
        float p = d1 * d2, q = d3 * d4;
        float n12 = fmaf(vq.y, d1, vq.x * d2);
        float n34 = fmaf(vq.w, d3, vq.z * d4);
        float N = fmaf(n34, p, n12 * q);
        float r = __builtin_amdgcn_rcpf(p * q);
        p1[t] = fmaf(N, r, p1[t]);
      }
    }
  }

  *(float4*)&part[0][wv][lane << 2] = *(float4*)p0;
  *(float4*)&part[1][wv][lane << 2] = *(float4*)p1;
  __syncthreads();

  if (wv < 2) {  // wave w -> d = d0 + w
    float l4v[4] = {0.f, 0.f, 0.f, 0.f};
#pragma unroll
    for (int w = 0; w < 8; ++w) {
      float4 q = *(const float4*)&part[wv][w][lane << 2];
      l4v[0] += q.x; l4v[1] += q.y; l4v[2] += q.z; l4v[3] += q.w;
    }
#pragma unroll
    for (int q = 0; q < 4; ++q) l4v[q] = -2.f * l4v[q];   // shift-invariant
    float m = wave_max(fmaxf(fmaxf(l4v[0], l4v[1]), fmaxf(l4v[2], l4v[3])));
    float p[4];
    float s = 0.f;
#pragma unroll
    for (int q = 0; q < 4; ++q) {
      p[q] = __builtin_amdgcn_exp2f((l4v[q] - m) * LOG2E);
      s += p[q];
    }
    s = wave_sum(s);
    const float inv = 1.0f / s;
    float4 ov = {p[0] * inv, p[1] * inv, p[2] * inv, p[3] * inv};
    const size_t ro = (size_t)(b * TD_ + d0 + wv) * TE_ + (lane << 2);
    *(float4*)(e_out + ro) = ov;
    ushort4 ob = {f2bf(ov.x), f2bf(ov.y), f2bf(ov.z), f2bf(ov.w)};
    *(ushort4*)(eB + ro) = ob;
  }
}

// ---------------------------------------------------------------------------
extern "C" void kernel_launch(void* const* d_in, const int* in_sizes, int n_in,
                              void* d_out, int out_size, void* d_ws, size_t ws_size,
                              hipStream_t stream) {
  const float* enc = (const float*)d_in[0];  // [B, TE, H]
  const float* dec = (const float*)d_in[1];  // [B, TD, H]
  const float* Wa  = (const float*)d_in[2];  // [H, H]
  const float* Ua  = (const float*)d_in[3];  // [H, H]
  const float* Va  = (const float*)d_in[4];  // [H]

  float* out_c = (float*)d_out;                       // [B, TD, H]
  float* out_e = out_c + (size_t)B_ * TD_ * H_;       // [B, TD, TE]

  char* w8 = (char*)d_ws;                             // 9 MB used
  ushort* E_T = (ushort*)(w8);                        // [B][H][TE] bf16  4 MB
  float*  eU  = (float*)(w8 + (4u << 20));            // [B][TD][H] f32   4 MB
  ushort* eB  = (ushort*)(w8 + (8u << 20));           // [B][TD][TE]bf16  1 MB

  // A1(flipped)+A2 fused, BM64/BN128/BK64 core (16 MFMA per barrier pair)
  gemm_phaseA<<<384, 256, 0, stream>>>(enc, Wa, E_T, dec, Ua, eU);

  // B: energies + softmax (round-13 scalar 4-way merge) -> out_e + eB
  energies_softmax<<<1024, 512, 0, stream>>>(E_T, eU, Va, out_e, eB);

  // C: c[b] = e[b] @ enc[b] (enc transposed in staging), BN=128
  gemm_ctx<<<dim3(4, 2, 16), 256, 0, stream>>>(eB, enc, out_c);
}

// Round 16
// 50.958 us; speedup vs baseline: 1.1969x; 1.1969x over previous
//
#include <hip/hip_runtime.h>

// Problem shapes (fixed by setup_inputs)
#define B_  16
#define TE_ 256
#define TD_ 128
#define H_  512

#define C_TANH 2.88539008177792681472f  // 2*log2(e):  tanh(x) = 1 - 2/(exp2(C*x)+1)
#define LOG2E  1.44269504088896340736f

typedef __attribute__((ext_vector_type(8))) short short8v;   // 8 x bf16 (4 VGPR)
typedef __attribute__((ext_vector_type(4))) float floatx4;   // MFMA acc

__device__ __forceinline__ float wave_sum(float v) {
#pragma unroll
  for (int m = 32; m; m >>= 1) v += __shfl_xor(v, m, 64);
  return v;
}
__device__ __forceinline__ float wave_max(float v) {
#pragma unroll
  for (int m = 32; m; m >>= 1) v = fmaxf(v, __shfl_xor(v, m, 64));
  return v;
}
__device__ __forceinline__ ushort f2bf(float f) {  // RNE fp32->bf16
  unsigned u = __builtin_bit_cast(unsigned, f);
  u += 0x7fffu + ((u >> 16) & 1u);
  return (ushort)(u >> 16);
}
__device__ __forceinline__ float bf2f(ushort u) {
  return __builtin_bit_cast(float, (unsigned)u << 16);
}
__device__ __forceinline__ unsigned pk2(float a, float b) {
  return (unsigned)f2bf(a) | ((unsigned)f2bf(b) << 16);
}

// ---------------------------------------------------------------------------
// GEMM core: BM=64 BN=64 BK=64, 4 waves (256 thr), 2-phase reg pipeline.
// LDS per operand: [2 k-slices][64 rows][pitch 40 ushort].
// Operand modes (MA/MB):
//   0 = bf16 row-major [n][k] direct
//   1 = f32  row-major [n][k], bf16-convert during staging
//   2 = f32  [k][n] source, TRANSPOSED during staging
// ---------------------------------------------------------------------------
template <int MA, int MB>
__device__ __forceinline__ void gemm_core(
    const void* Asrc, const void* Bsrc, long lda, long ldb, int K,
    int arow0, int brow0, ushort* As, ushort* Bs, floatx4* acc)
{
  const int tid = threadIdx.x;
  const int l = tid & 63, w = tid >> 6;
  const int l15 = l & 15, l4 = l >> 4;
  const int srow = tid >> 3, kg = tid & 7;
  const int dsRC = (kg >> 2) * 2560 + ((kg & 3) << 3);   // + row*40
  const int kp = tid >> 3, hg = tid & 7;                 // kp 0..31, hg 0..7
  const int dsT = (kp >> 4) * 2560 + ((kp << 1) & 31);   // + h*40

  const float*  Af = (const float*)Asrc;
  const ushort* Ab = (const ushort*)Asrc;
  const float*  Bf = (const float*)Bsrc;
  const ushort* Bb = (const ushort*)Bsrc;

  const long aoff0 = (long)(arow0 + srow) * lda + kg * 8;
  const long aoff1 = (long)(arow0 + 32 + srow) * lda + kg * 8;
  const long boff0 = (long)(brow0 + srow) * ldb + kg * 8;
  const long boff1 = (long)(brow0 + 32 + srow) * ldb + kg * 8;

  short8v a0r, a1r, b0r, b1r;
  float4 fa0, fa1, fa2, fa3, fb0, fb1, fb2, fb3;

  auto LD = [&](int kt) {
    if constexpr (MA == 0) {
      a0r = *(const short8v*)(Ab + aoff0 + kt);
      a1r = *(const short8v*)(Ab + aoff1 + kt);
    } else if constexpr (MA == 1) {
      fa0 = *(const float4*)(Af + aoff0 + kt);
      fa1 = *(const float4*)(Af + aoff0 + kt + 4);
      fa2 = *(const float4*)(Af + aoff1 + kt);
      fa3 = *(const float4*)(Af + aoff1 + kt + 4);
    } else {
      const long base = (long)(kt + 2 * kp) * lda + arow0 + hg * 8;
      fa0 = *(const float4*)(Af + base);
      fa1 = *(const float4*)(Af + base + 4);
      fa2 = *(const float4*)(Af + base + lda);
      fa3 = *(const float4*)(Af + base + lda + 4);
    }
    if constexpr (MB == 0) {
      b0r = *(const short8v*)(Bb + boff0 + kt);
      b1r = *(const short8v*)(Bb + boff1 + kt);
    } else if constexpr (MB == 1) {
      fb0 = *(const float4*)(Bf + boff0 + kt);
      fb1 = *(const float4*)(Bf + boff0 + kt + 4);
      fb2 = *(const float4*)(Bf + boff1 + kt);
      fb3 = *(const float4*)(Bf + boff1 + kt + 4);
    } else {
      const long base = (long)(kt + 2 * kp) * ldb + brow0 + hg * 8;
      fb0 = *(const float4*)(Bf + base);
      fb1 = *(const float4*)(Bf + base + 4);
      fb2 = *(const float4*)(Bf + base + ldb);
      fb3 = *(const float4*)(Bf + base + ldb + 4);
    }
  };
  auto ST = [&]() {
    if constexpr (MA == 0) {
      *(short8v*)&As[dsRC + srow * 40] = a0r;
      *(short8v*)&As[dsRC + (32 + srow) * 40] = a1r;
    } else if constexpr (MA == 1) {
      uint4 p0 = {pk2(fa0.x, fa0.y), pk2(fa0.z, fa0.w),
                  pk2(fa1.x, fa1.y), pk2(fa1.z, fa1.w)};
      uint4 p1 = {pk2(fa2.x, fa2.y), pk2(fa2.z, fa2.w),
                  pk2(fa3.x, fa3.y), pk2(fa3.z, fa3.w)};
      *(uint4*)&As[dsRC + srow * 40] = p0;
      *(uint4*)&As[dsRC + (32 + srow) * 40] = p1;
    } else {
      const int h0 = hg * 8;
      *(unsigned*)&As[dsT + (h0 + 0) * 40] = pk2(fa0.x, fa2.x);
      *(unsigned*)&As[dsT + (h0 + 1) * 40] = pk2(fa0.y, fa2.y);
      *(unsigned*)&As[dsT + (h0 + 2) * 40] = pk2(fa0.z, fa2.z);
      *(unsigned*)&As[dsT + (h0 + 3) * 40] = pk2(fa0.w, fa2.w);
      *(unsigned*)&As[dsT + (h0 + 4) * 40] = pk2(fa1.x, fa3.x);
      *(unsigned*)&As[dsT + (h0 + 5) * 40] = pk2(fa1.y, fa3.y);
      *(unsigned*)&As[dsT + (h0 + 6) * 40] = pk2(fa1.z, fa3.z);
      *(unsigned*)&As[dsT + (h0 + 7) * 40] = pk2(fa1.w, fa3.w);
    }
    if constexpr (MB == 0) {
      *(short8v*)&Bs[dsRC + srow * 40] = b0r;
      *(short8v*)&Bs[dsRC + (32 + srow) * 40] = b1r;
    } else if constexpr (MB == 1) {
      uint4 p0 = {pk2(fb0.x, fb0.y), pk2(fb0.z, fb0.w),
                  pk2(fb1.x, fb1.y), pk2(fb1.z, fb1.w)};
      uint4 p1 = {pk2(fb2.x, fb2.y), pk2(fb2.z, fb2.w),
                  pk2(fb3.x, fb3.y), pk2(fb3.z, fb3.w)};
      *(uint4*)&Bs[dsRC + srow * 40] = p0;
      *(uint4*)&Bs[dsRC + (32 + srow) * 40] = p1;
    } else {
      const int h0 = hg * 8;
      *(unsigned*)&Bs[dsT + (h0 + 0) * 40] = pk2(fb0.x, fb2.x);
      *(unsigned*)&Bs[dsT + (h0 + 1) * 40] = pk2(fb0.y, fb2.y);
      *(unsigned*)&Bs[dsT + (h0 + 2) * 40] = pk2(fb0.z, fb2.z);
      *(unsigned*)&Bs[dsT + (h0 + 3) * 40] = pk2(fb0.w, fb2.w);
      *(unsigned*)&Bs[dsT + (h0 + 4) * 40] = pk2(fb1.x, fb3.x);
      *(unsigned*)&Bs[dsT + (h0 + 5) * 40] = pk2(fb1.y, fb3.y);
      *(unsigned*)&Bs[dsT + (h0 + 6) * 40] = pk2(fb1.z, fb3.z);
      *(unsigned*)&Bs[dsT + (h0 + 7) * 40] = pk2(fb1.w, fb3.w);
    }
  };

  LD(0);
  for (int kt = 0; kt < K; kt += 64) {
    if (kt) __syncthreads();
    ST();
    __syncthreads();
    if (kt + 64 < K) LD(kt + 64);   // flies under the MFMAs
#pragma unroll
    for (int kk = 0; kk < 2; ++kk) {
      short8v av = *(short8v*)&As[kk * 2560 + (w * 16 + l15) * 40 + l4 * 8];
#pragma unroll
      for (int nt = 0; nt < 4; ++nt) {
        short8v bv = *(short8v*)&Bs[kk * 2560 + (nt * 16 + l15) * 40 + l4 * 8];
        acc[nt] = __builtin_amdgcn_mfma_f32_16x16x32_bf16(av, bv, acc[nt], 0, 0, 0);
      }
    }
  }
}

// ---------------------------------------------------------------------------
// Fused phase-A, 768 blocks, XCD-aligned with energies consumer (id&7 = XCD
// -> b in {2x,2x+1}). Wa/Ua staged transposed on the fly.
// ---------------------------------------------------------------------------
__global__ __launch_bounds__(256) void gemm_phaseA(
    const float* __restrict__ enc, const float* __restrict__ Wa,
    ushort* __restrict__ E_T,
    const float* __restrict__ dec, const float* __restrict__ Ua,
    float* __restrict__ eU)
{
  __shared__ __attribute__((aligned(16))) ushort As[5120];
  __shared__ __attribute__((aligned(16))) ushort Bs[5120];

  const int tid = threadIdx.x;
  const int l = tid & 63, w = tid >> 6;
  const int l15 = l & 15, l4 = l >> 4;
  const int id = blockIdx.x;

  floatx4 acc[4] = {};

  if (id < 512) {
    const int x = id & 7, k = id >> 3;
    const int bm = k >> 3;               // h-tile 0..7
    const int bn = x * 8 + (k & 7);      // m-tile 0..63 (b = bn>>2)
    gemm_core<2, 1>(Wa, enc, H_, H_, H_, bm * 64, bn * 64, As, Bs, acc);
    const int bb = bn >> 2, t0 = (bn & 3) * 64;
    const int hb = bm * 64 + w * 16 + (l4 << 2);
#pragma unroll
    for (int nt = 0; nt < 4; ++nt) {
      const int t = t0 + nt * 16 + l15;
#pragma unroll
      for (int r = 0; r < 4; ++r)
        E_T[((size_t)bb * H_ + hb + r) * TE_ + t] =
            f2bf(__builtin_amdgcn_exp2f(C_TANH * acc[nt][r]));
    }
  } else {
    const int i2 = id - 512;
    const int x = i2 & 7, k = i2 >> 3;
    const int bm = x * 4 + (k & 3);      // m-tile 0..31 (b = bm>>1)
    const int bn = k >> 2;               // h-tile 0..7
    gemm_core<1, 2>(dec, Ua, H_, H_, H_, bm * 64, bn * 64, As, Bs, acc);
    const int growb = bm * 64 + w * 16 + (l4 << 2);
#pragma unroll
    for (int nt = 0; nt < 4; ++nt) {
      const int gcol = bn * 64 + nt * 16 + l15;
#pragma unroll
      for (int r = 0; r < 4; ++r)
        eU[(size_t)(growb + r) * H_ + gcol] =
            __builtin_amdgcn_exp2f(C_TANH * acc[nt][r]);
    }
  }
}

// ---------------------------------------------------------------------------
// Phase-C GEMM: c[b] = eB[b] @ enc[b], enc staged transposed (mode 2).
// ---------------------------------------------------------------------------
__global__ __launch_bounds__(256) void gemm_ctx(
    const ushort* __restrict__ eB, const float* __restrict__ enc,
    float* __restrict__ C)
{
  __shared__ __attribute__((aligned(16))) ushort As[5120];
  __shared__ __attribute__((aligned(16))) ushort Bs[5120];

  const int tid = threadIdx.x;
  const int l = tid & 63, w = tid >> 6;
  const int l15 = l & 15, l4 = l >> 4;
  const long z = blockIdx.z;
  const int bm = blockIdx.y, bn = blockIdx.x;

  floatx4 acc[4] = {};
  gemm_core<0, 2>(eB + z * TD_ * TE_, enc + z * (long)TE_ * H_,
                  TE_, H_, TE_, bm * 64, bn * 64, As, Bs, acc);

  const int growb = bm * 64 + w * 16 + (l4 << 2);
#pragma unroll
  for (int nt = 0; nt < 4; ++nt) {
    const int gcol = bn * 64 + nt * 16 + l15;
#pragma unroll
    for (int r = 0; r < 4; ++r)
      C[(z * TD_ + growb + r) * (long)H_ + gcol] = acc[nt][r];
  }
}

// ---------------------------------------------------------------------------
// Energies + softmax, 4-way h-merged reciprocal (1 rcp per 4 elements):
//   Sum_{i=0..3} V_i/d_i = [(V0 d1 + V1 d0)q + (V2 d3 + V3 d2)p] / (p q),
//   p = d0 d1, q = d2 d3, d_i = 1 + E_i * U_i  (all d_i >= 1, product < 2^52,
//   no overflow; a few ulp rel. error, far under the 5e-3 budget).
// softmax is shift-invariant, so the sum(V) constant is dropped: l = -2p.
// 1024 blocks (XCD x -> b in {2x,2x+1}), 8 waves; block = (b, 2 d rows);
// wave w owns h in [64w,64w+64) for both d rows; lane owns t-quad.
// ---------------------------------------------------------------------------
__global__ __launch_bounds__(512) void energies_softmax(
    const ushort* __restrict__ E_T, const float* __restrict__ eU,
    const float* __restrict__ Va, float* __restrict__ e_out,
    ushort* __restrict__ eB)
{
  __shared__ float part[2][8][TE_];

  const int tid  = threadIdx.x;
  const int lane = tid & 63;
  const int wv   = __builtin_amdgcn_readfirstlane(tid >> 6);  // h-eighth
  const int id   = blockIdx.x;            // 0..1023
  const int xcd  = id & 7, j = id >> 3;   // XCD x -> b in {2x, 2x+1}
  const int b    = (xcd << 1) | (j >> 6);
  const int d0   = (j & 63) << 1;

  const float* u0 = eU + (size_t)(b * TD_ + d0 + 0) * H_ + wv * 64;
  const float* u1 = eU + (size_t)(b * TD_ + d0 + 1) * H_ + wv * 64;
  const float* vp = Va + wv * 64;
  const ushort* ep = E_T + ((size_t)(b * H_) + wv * 64) * TE_ + (lane << 2);

  float p0[4] = {}, p1[4] = {};

#pragma unroll 2
  for (int hq = 0; hq < 16; ++hq) {
    const float4 vq  = *(const float4*)(vp + hq * 4);
    const float4 uq0 = *(const float4*)(u0 + hq * 4);
    const float4 uq1 = *(const float4*)(u1 + hq * 4);
    const ushort4 w0 = *(const ushort4*)(ep + (size_t)(hq * 4 + 0) * TE_);
    const ushort4 w1 = *(const ushort4*)(ep + (size_t)(hq * 4 + 1) * TE_);
    const ushort4 w2 = *(const ushort4*)(ep + (size_t)(hq * 4 + 2) * TE_);
    const ushort4 w3 = *(const ushort4*)(ep + (size_t)(hq * 4 + 3) * TE_);
    const float eh0[4] = {bf2f(w0.x), bf2f(w0.y), bf2f(w0.z), bf2f(w0.w)};
    const float eh1[4] = {bf2f(w1.x), bf2f(w1.y), bf2f(w1.z), bf2f(w1.w)};
    const float eh2[4] = {bf2f(w2.x), bf2f(w2.y), bf2f(w2.z), bf2f(w2.w)};
    const float eh3[4] = {bf2f(w3.x), bf2f(w3.y), bf2f(w3.z), bf2f(w3.w)};
#pragma unroll
    for (int t = 0; t < 4; ++t) {
      {  // d-row 0
        float d1 = fmaf(eh0[t], uq0.x, 1.f);
        float d2 = fmaf(eh1[t], uq0.y, 1.f);
        float d3 = fmaf(eh2[t], uq0.z, 1.f);
        float d4 = fmaf(eh3[t], uq0.w, 1.f);
        float p = d1 * d2, q = d3 * d4;
        float n12 = fmaf(vq.y, d1, vq.x * d2);
        float n34 = fmaf(vq.w, d3, vq.z * d4);
        float N = fmaf(n34, p, n12 * q);
        float r = __builtin_amdgcn_rcpf(p * q);
        p0[t] = fmaf(N, r, p0[t]);
      }
      {  // d-row 1
        float d1 = fmaf(eh0[t], uq1.x, 1.f);
        float d2 = fmaf(eh1[t], uq1.y, 1.f);
        float d3 = fmaf(eh2[t], uq1.z, 1.f);
        float d4 = fmaf(eh3[t], uq1.w, 1.f);
        float p = d1 * d2, q = d3 * d4;
        float n12 = fmaf(vq.y, d1, vq.x * d2);
        float n34 = fmaf(vq.w, d3, vq.z * d4);
        float N = fmaf(n34, p, n12 * q);
        float r = __builtin_amdgcn_rcpf(p * q);
        p1[t] = fmaf(N, r, p1[t]);
      }
    }
  }

  *(float4*)&part[0][wv][lane << 2] = *(float4*)p0;
  *(float4*)&part[1][wv][lane << 2] = *(float4*)p1;
  __syncthreads();

  if (wv < 2) {  // wave w -> d = d0 + w
    float l4v[4] = {0.f, 0.f, 0.f, 0.f};
#pragma unroll
    for (int w = 0; w < 8; ++w) {
      float4 q = *(const float4*)&part[wv][w][lane << 2];
      l4v[0] += q.x; l4v[1] += q.y; l4v[2] += q.z; l4v[3] += q.w;
    }
#pragma unroll
    for (int q = 0; q < 4; ++q) l4v[q] = -2.f * l4v[q];   // shift-invariant
    float m = wave_max(fmaxf(fmaxf(l4v[0], l4v[1]), fmaxf(l4v[2], l4v[3])));
    float p[4];
    float s = 0.f;
#pragma unroll
    for (int q = 0; q < 4; ++q) {
      p[q] = __builtin_amdgcn_exp2f((l4v[q] - m) * LOG2E);
      s += p[q];
    }
    s = wave_sum(s);
    const float inv = 1.0f / s;
    float4 ov = {p[0] * inv, p[1] * inv, p[2] * inv, p[3] * inv};
    const size_t ro = (size_t)(b * TD_ + d0 + wv) * TE_ + (lane << 2);
    *(float4*)(e_out + ro) = ov;
    ushort4 ob = {f2bf(ov.x), f2bf(ov.y), f2bf(ov.z), f2bf(ov.w)};
    *(ushort4*)(eB + ro) = ob;
  }
}

// ---------------------------------------------------------------------------
extern "C" void kernel_launch(void* const* d_in, const int* in_sizes, int n_in,
                              void* d_out, int out_size, void* d_ws, size_t ws_size,
                              hipStream_t stream) {
  const float* enc = (const float*)d_in[0];  // [B, TE, H]
  const float* dec = (const float*)d_in[1];  // [B, TD, H]
  const float* Wa  = (const float*)d_in[2];  // [H, H]
  const float* Ua  = (const float*)d_in[3];  // [H, H]
  const float* Va  = (const float*)d_in[4];  // [H]

  float* out_c = (float*)d_out;                       // [B, TD, H]
  float* out_e = out_c + (size_t)B_ * TD_ * H_;       // [B, TD, TE]

  char* w8 = (char*)d_ws;                             // 9 MB used
  ushort* E_T = (ushort*)(w8);                        // [B][H][TE] bf16  4 MB
  float*  eU  = (float*)(w8 + (4u << 20));            // [B][TD][H] f32   4 MB
  ushort* eB  = (ushort*)(w8 + (8u << 20));           // [B][TD][TE]bf16  1 MB

  // A1(flipped)+A2 fused, BK=64 core, transposes folded into staging
  gemm_phaseA<<<768, 256, 0, stream>>>(enc, Wa, E_T, dec, Ua, eU);

  // B: energies + softmax (4-way h-merged rcp) -> out_e (f32) + eB (bf16)
  energies_softmax<<<1024, 512, 0, stream>>>(E_T, eU, Va, out_e, eB);

  // C: c[b] = e[b] @ enc[b] (enc transposed in staging)
  gemm_ctx<<<dim3(8, 2, 16), 256, 0, stream>>>(eB, enc, out_c);
}